// Round 6
// baseline (175.796 us; speedup 1.0000x reference)
//
#include <hip/hip_runtime.h>

// LSTM autoencoder via bf16 MFMA, v4: 1024-thr blocks (16 waves), 32 waves/CU.
// B=8192, T=30, F=16, H1=64, H2=32. Grid 512, BT=16 batches/block, 2 blocks/CU.
// Work split per step (skewed pipeline, 1 barrier/step):
//   all 16 waves: one z1 (phase A) / z4 (phase B) tile = 4 units;
//   waves 8..15:  additionally one z2 / z3 tile; waves 0..7: output projection.
// Biases live in LDS (ds_read_b128 -> MFMA C operand); weights in registers.
// Step loops unrolled x2 so dbuf offsets are compile-time.
// aB slots (stride 264): phA h1 dbuf p*64, h2 dbuf 128+p*32, latent ->160;
//                        phB h4 dbuf p*64, latent 160..191, h3 dbuf 192+p*32.
// LDS: xAll 30.2KB + aB 8.25KB + bSS 3.06KB = ~41.6KB -> 2 blocks/CU.

#define TT 30
#define FF 16

typedef unsigned short u16t;
typedef __attribute__((ext_vector_type(8))) short short8;
typedef __attribute__((ext_vector_type(4))) short short4v;
typedef __attribute__((ext_vector_type(4))) float floatx4;

#define MFMA(a, b, c) __builtin_amdgcn_mfma_f32_16x16x32_bf16(a, b, c, 0, 0, 0)

template <int P> struct IC { static constexpr int v = P; };

__device__ __forceinline__ float rcpf(float v) { return __builtin_amdgcn_rcpf(v); }
__device__ __forceinline__ float sigf(float v) { return rcpf(1.f + __expf(-v)); }
__device__ __forceinline__ float tanhf_(float v) { return 1.f - 2.f * rcpf(1.f + __expf(2.f * v)); }
__device__ __forceinline__ u16t f2bf(float f) {
  unsigned int u = __float_as_uint(f);
  u = (u + 0x7FFFu + ((u >> 16) & 1u)) >> 16;
  return (u16t)u;
}
__device__ __forceinline__ short8 ldFrag(const float* p) {
  const float4 lo = *(const float4*)p;
  const float4 hi = *(const float4*)(p + 4);
  short8 r;
  r[0] = (short)f2bf(lo.x); r[1] = (short)f2bf(lo.y);
  r[2] = (short)f2bf(lo.z); r[3] = (short)f2bf(lo.w);
  r[4] = (short)f2bf(hi.x); r[5] = (short)f2bf(hi.y);
  r[6] = (short)f2bf(hi.z); r[7] = (short)f2bf(hi.w);
  return r;
}
// lane owns gates i,f,g,o of one (unit,batch): acc regs 0..3
__device__ __forceinline__ float cellUp(const floatx4 acc, float& c) {
  float iv = sigf(acc[0]), fv = sigf(acc[1]);
  float gv = tanhf_(acc[2]), ov = sigf(acc[3]);
  c = fv * c + iv * gv;
  return ov * tanhf_(c);
}

__global__ __launch_bounds__(1024, 8) void lstm_ae_mfma4(
    const float* __restrict__ x,
    const float* __restrict__ Wih1, const float* __restrict__ Whh1, const float* __restrict__ b1,
    const float* __restrict__ Wih2, const float* __restrict__ Whh2, const float* __restrict__ b2,
    const float* __restrict__ Wih3, const float* __restrict__ Whh3, const float* __restrict__ b3,
    const float* __restrict__ Wih4, const float* __restrict__ Whh4, const float* __restrict__ b4,
    const float* __restrict__ Wout, const float* __restrict__ bout,
    float* __restrict__ out)
{
  __shared__ __align__(16) u16t xAll[16 * 968];  // x bf16, k16..31 zero-pad, stride 968
  __shared__ __align__(16) u16t aB[16 * 264];    // recurrent state, stride 264
  __shared__ __align__(16) float bSS[784];       // permuted biases (per-tile, per-quad)

  const int t = threadIdx.x;
  const int w = t >> 6, lane = t & 63;           // 16 waves
  const int q = lane >> 4, n = lane & 15;
  const int q8 = q * 8, n264 = n * 264, n968 = n * 968;
  const int bBase = blockIdx.x * 16;
  const int nlo = n >> 2, ngt = n & 3;
  const u16t* aRow = &aB[n264];
  const bool heavy = (w >= 8);
  const int wh = w & 7;

  // ================= init =================
  for (int i = t; i < 16 * 264; i += 1024) aB[i] = 0;
  {
    const float* xb = x + (size_t)bBase * (TT * FF);
    for (int i4 = t; i4 < 1920; i4 += 1024) {
      int e = i4 * 4;
      int b = e / 480, r = e - b * 480;
      int stp = r >> 4, f = r & 15;
      float4 v = *(const float4*)&xb[e];
      short4v s4 = { (short)f2bf(v.x), (short)f2bf(v.y), (short)f2bf(v.z), (short)f2bf(v.w) };
      *(short4v*)&xAll[b * 968 + stp * 32 + f] = s4;
    }
    for (int i = t; i < 7680; i += 1024) {  // zero pads k=16..31
      int b = i / 480, r = i - b * 480;
      int stp = r >> 4, f = r & 15;
      xAll[b * 968 + stp * 32 + 16 + f] = 0;
    }
  }
  for (int i = t; i < 784; i += 1024) {  // permuted biases -> LDS
    float v;
    if (i < 256)      { int T = i >> 4, rm = i & 15;      v = b1[(rm & 3) * 64 + T * 4 + (rm >> 2)]; }
    else if (i < 384) { int j = i - 256, T = j >> 4, rm = j & 15; v = b2[(rm & 3) * 32 + T * 4 + (rm >> 2)]; }
    else if (i < 512) { int j = i - 384, T = j >> 4, rm = j & 15; v = b3[(rm & 3) * 32 + T * 4 + (rm >> 2)]; }
    else if (i < 768) { int j = i - 512, T = j >> 4, rm = j & 15; v = b4[(rm & 3) * 64 + T * 4 + (rm >> 2)]; }
    else              { v = bout[i - 768]; }
    bSS[i] = v;
  }
  const short8 z8 = { 0, 0, 0, 0, 0, 0, 0, 0 };
  short8 w1f[3];
  {
    int row = ngt * 64 + w * 4 + nlo;   // z1 tile w (units 4w..4w+3)
    w1f[0] = z8;
    if (q < 2) w1f[0] = ldFrag(&Wih1[row * 16 + q8]);
    w1f[1] = ldFrag(&Whh1[row * 64 + q8]);
    w1f[2] = ldFrag(&Whh1[row * 64 + 32 + q8]);
  }
  short8 w2f[3];
  if (heavy) {
    int row = ngt * 32 + wh * 4 + nlo;  // z2 tile wh
    w2f[0] = ldFrag(&Wih2[row * 64 + q8]);
    w2f[1] = ldFrag(&Wih2[row * 64 + 32 + q8]);
    w2f[2] = ldFrag(&Whh2[row * 32 + q8]);
  } else { w2f[0] = z8; w2f[1] = z8; w2f[2] = z8; }
  __syncthreads();

  float c1v = 0.f, c2v = 0.f;

  // ---- peel z1(0): h1(-1)=0 ----
  {
    const short8 bx = *(const short8*)&xAll[n968 + q8];
    floatx4 a0 = *(const floatx4*)&bSS[w * 16 + q * 4];
    a0 = MFMA(w1f[0], bx, a0);
    aB[n264 + w * 4 + q] = f2bf(cellUp(a0, c1v));
  }
  __syncthreads();

  // ================= Phase A: 29 skewed iters =================
  auto stepA = [&](int st, auto pc) {
    constexpr int p = decltype(pc)::v;
    const short8 bh1a = *(const short8*)&aRow[p * 64 + q8];
    const short8 bh1b = *(const short8*)&aRow[p * 64 + 32 + q8];
    const short8 bx   = *(const short8*)&xAll[n968 + (st + 1) * 32 + q8];
    floatx4 a0 = *(const floatx4*)&bSS[w * 16 + q * 4];       // z1(st+1)
    a0 = MFMA(w1f[0], bx, a0);
    a0 = MFMA(w1f[1], bh1a, a0);
    a0 = MFMA(w1f[2], bh1b, a0);
    if (heavy) {                                              // z2(st)
      const short8 bh2 = *(const short8*)&aRow[128 + (1 - p) * 32 + q8];
      floatx4 a2 = *(const floatx4*)&bSS[256 + wh * 16 + q * 4];
      a2 = MFMA(w2f[0], bh1a, a2);
      a2 = MFMA(w2f[1], bh1b, a2);
      a2 = MFMA(w2f[2], bh2, a2);
      aB[n264 + 128 + p * 32 + wh * 4 + q] = f2bf(cellUp(a2, c2v));
    }
    aB[n264 + (1 - p) * 64 + w * 4 + q] = f2bf(cellUp(a0, c1v));
    __syncthreads();
  };
  for (int st = 0; st < 28; st += 2) { stepA(st, IC<0>{}); stepA(st + 1, IC<1>{}); }
  stepA(28, IC<0>{});
  // ---- tail z2(29): h1(29) at 64.., h2(28) at 128 -> latent 160..191 ----
  if (heavy) {
    const short8 bh1a = *(const short8*)&aRow[64 + q8];
    const short8 bh1b = *(const short8*)&aRow[96 + q8];
    const short8 bh2  = *(const short8*)&aRow[128 + q8];
    floatx4 a2 = *(const floatx4*)&bSS[256 + wh * 16 + q * 4];
    a2 = MFMA(w2f[0], bh1a, a2);
    a2 = MFMA(w2f[1], bh1b, a2);
    a2 = MFMA(w2f[2], bh2, a2);
    aB[n264 + 160 + wh * 4 + q] = f2bf(cellUp(a2, c2v));
  }
  __syncthreads();

  // ================= transition: phase-B weights =================
  short8 w4f[3];
  {
    int row = ngt * 64 + w * 4 + nlo;   // z4 tile w
    w4f[0] = ldFrag(&Wih4[row * 32 + q8]);
    w4f[1] = ldFrag(&Whh4[row * 64 + q8]);
    w4f[2] = ldFrag(&Whh4[row * 64 + 32 + q8]);
  }
  short8 w3f[2];
  if (heavy) {
    int row = ngt * 32 + wh * 4 + nlo;  // z3 tile wh
    w3f[0] = ldFrag(&Wih3[row * 32 + q8]);
    w3f[1] = ldFrag(&Whh3[row * 32 + q8]);
  } else { w3f[0] = z8; w3f[1] = z8; }
  short8 wof[2];
  if (!heavy) {                         // projection on light waves
    wof[0] = ldFrag(&Wout[n * 64 + q8]);
    wof[1] = ldFrag(&Wout[n * 64 + 32 + q8]);
  } else { wof[0] = z8; wof[1] = z8; }
  const short8 blat = *(const short8*)&aRow[160 + q8];
  for (int i = t; i < 1024; i += 1024) aB[(i >> 6) * 264 + 64 + (i & 63)] = 0;  // h4(-1)=0
  __syncthreads();

  float c3v = 0.f, c4v = 0.f;

  // ---- peel z3(0): h3(-1)=0 ----
  if (heavy) {
    floatx4 a3 = *(const floatx4*)&bSS[384 + wh * 16 + q * 4];
    a3 = MFMA(w3f[0], blat, a3);
    aB[n264 + 192 + wh * 4 + q] = f2bf(cellUp(a3, c3v));
  }
  __syncthreads();

  // ================= Phase B: 29 skewed iters =================
  auto stepB = [&](int st, auto pc) {
    constexpr int p = decltype(pc)::v;
    const short8 bh3  = *(const short8*)&aRow[192 + p * 32 + q8];
    const short8 bh4a = *(const short8*)&aRow[(1 - p) * 64 + q8];
    const short8 bh4b = *(const short8*)&aRow[(1 - p) * 64 + 32 + q8];
    floatx4 a4 = *(const floatx4*)&bSS[512 + w * 16 + q * 4];  // z4(st)
    a4 = MFMA(w4f[0], bh3, a4);
    a4 = MFMA(w4f[1], bh4a, a4);
    a4 = MFMA(w4f[2], bh4b, a4);
    if (heavy) {                                               // z3(st+1)
      floatx4 a3 = *(const floatx4*)&bSS[384 + wh * 16 + q * 4];
      a3 = MFMA(w3f[0], blat, a3);
      a3 = MFMA(w3f[1], bh3, a3);
      aB[n264 + 192 + (1 - p) * 32 + wh * 4 + q] = f2bf(cellUp(a3, c3v));
    }
    aB[n264 + p * 64 + w * 4 + q] = f2bf(cellUp(a4, c4v));
    if (!heavy && st > 0 && w == ((st - 1) & 7)) {             // proj(st-1)
      floatx4 yv = *(const floatx4*)&bSS[768 + q * 4];
      yv = MFMA(wof[0], bh4a, yv);
      yv = MFMA(wof[1], bh4b, yv);
      *(floatx4*)&out[((size_t)(bBase + n) * TT + (st - 1)) * FF + q * 4] = yv;
    }
    __syncthreads();
  };
  for (int st = 0; st < 28; st += 2) { stepB(st, IC<0>{}); stepB(st + 1, IC<1>{}); }
  stepB(28, IC<0>{});
  // ---- tail: z4(29) (h3(29)@224, h4(28)@0); proj(28); proj(29) ----
  {
    const short8 bh3  = *(const short8*)&aRow[224 + q8];
    const short8 bh4a = *(const short8*)&aRow[q8];
    const short8 bh4b = *(const short8*)&aRow[32 + q8];
    floatx4 a4 = *(const floatx4*)&bSS[512 + w * 16 + q * 4];
    a4 = MFMA(w4f[0], bh3, a4);
    a4 = MFMA(w4f[1], bh4a, a4);
    a4 = MFMA(w4f[2], bh4b, a4);
    aB[n264 + 64 + w * 4 + q] = f2bf(cellUp(a4, c4v));
    if (w == 4) {
      floatx4 yv = *(const floatx4*)&bSS[768 + q * 4];
      yv = MFMA(wof[0], bh4a, yv);
      yv = MFMA(wof[1], bh4b, yv);
      *(floatx4*)&out[((size_t)(bBase + n) * TT + 28) * FF + q * 4] = yv;
    }
  }
  __syncthreads();
  if (w == 5) {  // proj(29): h4(29) at 64/96
    const short8 ba = *(const short8*)&aRow[64 + q8];
    const short8 bb = *(const short8*)&aRow[96 + q8];
    floatx4 yv = *(const floatx4*)&bSS[768 + q * 4];
    yv = MFMA(wof[0], ba, yv);
    yv = MFMA(wof[1], bb, yv);
    *(floatx4*)&out[((size_t)(bBase + n) * TT + 29) * FF + q * 4] = yv;
  }
}

extern "C" void kernel_launch(void* const* d_in, const int* in_sizes, int n_in,
                              void* d_out, int out_size, void* d_ws, size_t ws_size,
                              hipStream_t stream) {
  const float* x    = (const float*)d_in[0];
  const float* Wih1 = (const float*)d_in[1];
  const float* Whh1 = (const float*)d_in[2];
  const float* b1   = (const float*)d_in[3];
  const float* Wih2 = (const float*)d_in[4];
  const float* Whh2 = (const float*)d_in[5];
  const float* b2   = (const float*)d_in[6];
  const float* Wih3 = (const float*)d_in[7];
  const float* Whh3 = (const float*)d_in[8];
  const float* b3   = (const float*)d_in[9];
  const float* Wih4 = (const float*)d_in[10];
  const float* Whh4 = (const float*)d_in[11];
  const float* b4   = (const float*)d_in[12];
  const float* Wout = (const float*)d_in[13];
  const float* bout = (const float*)d_in[14];
  float* out = (float*)d_out;

  const int B = in_sizes[0] / (TT * FF);   // 8192
  dim3 grid(B / 16), block(1024);
  lstm_ae_mfma4<<<grid, block, 0, stream>>>(
      x, Wih1, Whh1, b1, Wih2, Whh2, b2, Wih3, Whh3, b3,
      Wih4, Whh4, b4, Wout, bout, out);
}

// Round 7
// 169.257 us; speedup vs baseline: 1.0386x; 1.0386x over previous
//
#include <hip/hip_runtime.h>

// LSTM autoencoder via bf16 MFMA, v5 = v3 structure + unroll + x-prefetch + anti-phase.
// B=8192, T=30, F=16, H1=64, H2=32. Grid 512 x 512 thr, 16 batches/block, 2 blocks/CU.
// Skew: z2(st)+z1(st+1) share h1(st) frags -> 1 barrier/step; decoder same with proj.
// Weights/biases in registers (unit-major permute row=unit*4+gate).
// aB slots (stride 264 u16): phA h1 dbuf p*64, h2 dbuf 128+p*32, latent 160;
//                            phB h4 dbuf p*64, latent 160 (preserved), h3 dbuf 192+p*32.
// LDS: xAll 16x968 (30.2KB) + aB 16x264 (8.25KB) = 38.5KB.

#define TT 30
#define FF 16

typedef unsigned short u16t;
typedef __attribute__((ext_vector_type(8))) short short8;
typedef __attribute__((ext_vector_type(4))) short short4v;
typedef __attribute__((ext_vector_type(4))) float floatx4;

#define MFMA(a, b, c) __builtin_amdgcn_mfma_f32_16x16x32_bf16(a, b, c, 0, 0, 0)

template <int P> struct IC { static constexpr int v = P; };

__device__ __forceinline__ float rcpf(float v) { return __builtin_amdgcn_rcpf(v); }
__device__ __forceinline__ float sigf(float v) { return rcpf(1.f + __expf(-v)); }
__device__ __forceinline__ float tanhf_(float v) { return 1.f - 2.f * rcpf(1.f + __expf(2.f * v)); }
__device__ __forceinline__ u16t f2bf(float f) {
  unsigned int u = __float_as_uint(f);
  u = (u + 0x7FFFu + ((u >> 16) & 1u)) >> 16;
  return (u16t)u;
}
__device__ __forceinline__ short8 ldFrag(const float* p) {
  const float4 lo = *(const float4*)p;
  const float4 hi = *(const float4*)(p + 4);
  short8 r;
  r[0] = (short)f2bf(lo.x); r[1] = (short)f2bf(lo.y);
  r[2] = (short)f2bf(lo.z); r[3] = (short)f2bf(lo.w);
  r[4] = (short)f2bf(hi.x); r[5] = (short)f2bf(hi.y);
  r[6] = (short)f2bf(hi.z); r[7] = (short)f2bf(hi.w);
  return r;
}
// lane owns gates i,f,g,o of one (unit,batch): acc regs 0..3
__device__ __forceinline__ float cellUp(const floatx4 acc, float& c) {
  float iv = sigf(acc[0]), fv = sigf(acc[1]);
  float gv = tanhf_(acc[2]), ov = sigf(acc[3]);
  c = fv * c + iv * gv;
  return ov * tanhf_(c);
}

__global__ __launch_bounds__(512, 4) void lstm_ae_mfma5(
    const float* __restrict__ x,
    const float* __restrict__ Wih1, const float* __restrict__ Whh1, const float* __restrict__ b1,
    const float* __restrict__ Wih2, const float* __restrict__ Whh2, const float* __restrict__ b2,
    const float* __restrict__ Wih3, const float* __restrict__ Whh3, const float* __restrict__ b3,
    const float* __restrict__ Wih4, const float* __restrict__ Whh4, const float* __restrict__ b4,
    const float* __restrict__ Wout, const float* __restrict__ bout,
    float* __restrict__ out)
{
  __shared__ __align__(16) u16t xAll[16 * 968];  // x bf16, k16..31 zero-pad, stride 968
  __shared__ __align__(16) u16t aB[16 * 264];    // recurrent state, stride 264

  const int t = threadIdx.x;
  const int w = t >> 6, lane = t & 63;
  const int q = lane >> 4, n = lane & 15;
  const int q8 = q * 8, n264 = n * 264, n968 = n * 968;
  const int bBase = blockIdx.x * 16;
  const int nlo = n >> 2, ngt = n & 3;
  const u16t* aRow = &aB[n264];

  // ================= init =================
  for (int i = t; i < 16 * 264; i += 512) aB[i] = 0;
  {
    const float* xb = x + (size_t)bBase * (TT * FF);
    for (int i4 = t; i4 < 1920; i4 += 512) {
      int e = i4 * 4;
      int b = e / 480, r = e - b * 480;
      int stp = r >> 4, f = r & 15;
      float4 v = *(const float4*)&xb[e];
      short4v s4 = { (short)f2bf(v.x), (short)f2bf(v.y), (short)f2bf(v.z), (short)f2bf(v.w) };
      *(short4v*)&xAll[b * 968 + stp * 32 + f] = s4;
    }
    for (int i = t; i < 7680; i += 512) {   // zero pads k=16..31
      int b = i / 480, r = i - b * 480;
      int stp = r >> 4, f = r & 15;
      xAll[b * 968 + stp * 32 + 16 + f] = 0;
    }
  }
  short8 w1f[2][3]; floatx4 bias1[2];
  const short8 z8 = { 0, 0, 0, 0, 0, 0, 0, 0 };
#pragma unroll
  for (int tt = 0; tt < 2; ++tt) {
    int row = ngt * 64 + (2 * w + tt) * 4 + nlo;
    w1f[tt][0] = z8;
    if (q < 2) w1f[tt][0] = ldFrag(&Wih1[row * 16 + q8]);
    w1f[tt][1] = ldFrag(&Whh1[row * 64 + q8]);
    w1f[tt][2] = ldFrag(&Whh1[row * 64 + 32 + q8]);
#pragma unroll
    for (int r = 0; r < 4; ++r) bias1[tt][r] = b1[r * 64 + (2 * w + tt) * 4 + q];
  }
  short8 w2f[3]; floatx4 bias2;
  {
    int row = ngt * 32 + w * 4 + nlo;
    w2f[0] = ldFrag(&Wih2[row * 64 + q8]);
    w2f[1] = ldFrag(&Wih2[row * 64 + 32 + q8]);
    w2f[2] = ldFrag(&Whh2[row * 32 + q8]);
#pragma unroll
    for (int r = 0; r < 4; ++r) bias2[r] = b2[r * 32 + w * 4 + q];
  }
  // anti-phase nudge: co-resident pair is likely (i, i+256) -> delay second wavefront-set
  if (blockIdx.x & 256) {
    __builtin_amdgcn_s_sleep(15);
    __builtin_amdgcn_s_sleep(15);
  }
  __syncthreads();

  float c1v[2] = {0.f, 0.f}, c2v = 0.f;

  // ---- peel: z1(0) (h1(-1)=0) ----
  {
    const short8 bx = *(const short8*)&xAll[n968 + q8];
    floatx4 a0 = bias1[0], a1 = bias1[1];
    a0 = MFMA(w1f[0][0], bx, a0); a1 = MFMA(w1f[1][0], bx, a1);
    aB[n264 + (2 * w) * 4 + q]     = f2bf(cellUp(a0, c1v[0]));
    aB[n264 + (2 * w + 1) * 4 + q] = f2bf(cellUp(a1, c1v[1]));
  }
  short8 bxN = *(const short8*)&xAll[n968 + 32 + q8];   // prefetch x(1)
  __syncthreads();

  // ================= Phase A: 29 skewed iters, 1 barrier each =================
  auto stepA = [&](int st, auto pc) {
    constexpr int p = decltype(pc)::v;
    const short8 bh1a = *(const short8*)&aRow[p * 64 + q8];
    const short8 bh1b = *(const short8*)&aRow[p * 64 + 32 + q8];
    const short8 bh2  = *(const short8*)&aRow[128 + (1 - p) * 32 + q8];
    // z2(st)
    floatx4 a2 = bias2;
    a2 = MFMA(w2f[0], bh1a, a2);
    a2 = MFMA(w2f[1], bh1b, a2);
    a2 = MFMA(w2f[2], bh2, a2);
    // z1(st+1) using prefetched bxN = x(st+1)
    floatx4 a0 = bias1[0], a1 = bias1[1];
    a0 = MFMA(w1f[0][0], bxN, a0);  a1 = MFMA(w1f[1][0], bxN, a1);
    a0 = MFMA(w1f[0][1], bh1a, a0); a1 = MFMA(w1f[1][1], bh1a, a1);
    a0 = MFMA(w1f[0][2], bh1b, a0); a1 = MFMA(w1f[1][2], bh1b, a1);
    // prefetch x(st+2) (clamped; xAll is read-only so this crosses the barrier safely)
    const int nx = (st + 2 < TT) ? st + 2 : TT - 1;
    bxN = *(const short8*)&xAll[n968 + nx * 32 + q8];
    aB[n264 + 128 + p * 32 + w * 4 + q]           = f2bf(cellUp(a2, c2v));
    aB[n264 + (1 - p) * 64 + (2 * w) * 4 + q]     = f2bf(cellUp(a0, c1v[0]));
    aB[n264 + (1 - p) * 64 + (2 * w + 1) * 4 + q] = f2bf(cellUp(a1, c1v[1]));
    __syncthreads();
  };
  for (int st = 0; st < 28; st += 2) { stepA(st, IC<0>{}); stepA(st + 1, IC<1>{}); }
  stepA(28, IC<0>{});
  // ---- tail: z2(29); h1(29)@64, h2(28)@128 -> latent 160..191 ----
  {
    const short8 bh1a = *(const short8*)&aRow[64 + q8];
    const short8 bh1b = *(const short8*)&aRow[96 + q8];
    const short8 bh2  = *(const short8*)&aRow[128 + q8];
    floatx4 a2 = bias2;
    a2 = MFMA(w2f[0], bh1a, a2);
    a2 = MFMA(w2f[1], bh1b, a2);
    a2 = MFMA(w2f[2], bh2, a2);
    aB[n264 + 160 + w * 4 + q] = f2bf(cellUp(a2, c2v));
  }
  __syncthreads();

  // ================= transition: phase-B weights/biases =================
  short8 w3f[2]; floatx4 bias3;
  {
    int row = ngt * 32 + w * 4 + nlo;
    w3f[0] = ldFrag(&Wih3[row * 32 + q8]);
    w3f[1] = ldFrag(&Whh3[row * 32 + q8]);
#pragma unroll
    for (int r = 0; r < 4; ++r) bias3[r] = b3[r * 32 + w * 4 + q];
  }
  short8 w4f[2][3]; floatx4 bias4[2];
#pragma unroll
  for (int tt = 0; tt < 2; ++tt) {
    int row = ngt * 64 + (2 * w + tt) * 4 + nlo;
    w4f[tt][0] = ldFrag(&Wih4[row * 32 + q8]);
    w4f[tt][1] = ldFrag(&Whh4[row * 64 + q8]);
    w4f[tt][2] = ldFrag(&Whh4[row * 64 + 32 + q8]);
#pragma unroll
    for (int r = 0; r < 4; ++r) bias4[tt][r] = b4[r * 64 + (2 * w + tt) * 4 + q];
  }
  short8 wof[2];
  wof[0] = ldFrag(&Wout[n * 64 + q8]);
  wof[1] = ldFrag(&Wout[n * 64 + 32 + q8]);
  const floatx4 biasO = *(const floatx4*)&bout[q * 4];
  const short8 blat = *(const short8*)&aRow[160 + q8];
  for (int i = t; i < 1024; i += 512) aB[(i >> 6) * 264 + 64 + (i & 63)] = 0;  // h4(-1)=0
  __syncthreads();

  float c3v = 0.f, c4v[2] = {0.f, 0.f};

  // ---- peel: z3(0) (h3(-1)=0) ----
  {
    floatx4 a3 = bias3;
    a3 = MFMA(w3f[0], blat, a3);
    aB[n264 + 192 + w * 4 + q] = f2bf(cellUp(a3, c3v));
  }
  __syncthreads();

  // ================= Phase B: 29 skewed iters, 1 barrier each =================
  auto stepB = [&](int st, auto pc) {
    constexpr int p = decltype(pc)::v;
    const short8 bh3  = *(const short8*)&aRow[192 + p * 32 + q8];
    const short8 bh4a = *(const short8*)&aRow[(1 - p) * 64 + q8];
    const short8 bh4b = *(const short8*)&aRow[(1 - p) * 64 + 32 + q8];
    // z4(st)
    floatx4 a40 = bias4[0], a41 = bias4[1];
    a40 = MFMA(w4f[0][0], bh3, a40);  a41 = MFMA(w4f[1][0], bh3, a41);
    a40 = MFMA(w4f[0][1], bh4a, a40); a41 = MFMA(w4f[1][1], bh4a, a41);
    a40 = MFMA(w4f[0][2], bh4b, a40); a41 = MFMA(w4f[1][2], bh4b, a41);
    // z3(st+1)
    floatx4 a3 = bias3;
    a3 = MFMA(w3f[0], blat, a3);
    a3 = MFMA(w3f[1], bh3, a3);
    aB[n264 + p * 64 + (2 * w) * 4 + q]     = f2bf(cellUp(a40, c4v[0]));
    aB[n264 + p * 64 + (2 * w + 1) * 4 + q] = f2bf(cellUp(a41, c4v[1]));
    aB[n264 + 192 + (1 - p) * 32 + w * 4 + q] = f2bf(cellUp(a3, c3v));
    // proj(st-1): rotating wave, reuses bh4a/bh4b = h4(st-1)
    if (st > 0 && w == ((st - 1) & 7)) {
      floatx4 yv = biasO;
      yv = MFMA(wof[0], bh4a, yv);
      yv = MFMA(wof[1], bh4b, yv);
      *(floatx4*)&out[((size_t)(bBase + n) * TT + (st - 1)) * FF + q * 4] = yv;
    }
    __syncthreads();
  };
  for (int st = 0; st < 28; st += 2) { stepB(st, IC<0>{}); stepB(st + 1, IC<1>{}); }
  stepB(28, IC<0>{});
  // ---- tail: z4(29) (h3(29)@224, h4(28)@0); proj(28); proj(29) ----
  {
    const short8 bh3  = *(const short8*)&aRow[224 + q8];
    const short8 bh4a = *(const short8*)&aRow[q8];
    const short8 bh4b = *(const short8*)&aRow[32 + q8];
    floatx4 a40 = bias4[0], a41 = bias4[1];
    a40 = MFMA(w4f[0][0], bh3, a40);  a41 = MFMA(w4f[1][0], bh3, a41);
    a40 = MFMA(w4f[0][1], bh4a, a40); a41 = MFMA(w4f[1][1], bh4a, a41);
    a40 = MFMA(w4f[0][2], bh4b, a40); a41 = MFMA(w4f[1][2], bh4b, a41);
    aB[n264 + 64 + (2 * w) * 4 + q]     = f2bf(cellUp(a40, c4v[0]));
    aB[n264 + 64 + (2 * w + 1) * 4 + q] = f2bf(cellUp(a41, c4v[1]));
    if (w == 4) {  // proj(28)
      floatx4 yv = biasO;
      yv = MFMA(wof[0], bh4a, yv);
      yv = MFMA(wof[1], bh4b, yv);
      *(floatx4*)&out[((size_t)(bBase + n) * TT + 28) * FF + q * 4] = yv;
    }
  }
  __syncthreads();
  if (w == 5) {  // proj(29): h4(29)@64/96
    const short8 ba = *(const short8*)&aRow[64 + q8];
    const short8 bb = *(const short8*)&aRow[96 + q8];
    floatx4 yv = biasO;
    yv = MFMA(wof[0], ba, yv);
    yv = MFMA(wof[1], bb, yv);
    *(floatx4*)&out[((size_t)(bBase + n) * TT + 29) * FF + q * 4] = yv;
  }
}

extern "C" void kernel_launch(void* const* d_in, const int* in_sizes, int n_in,
                              void* d_out, int out_size, void* d_ws, size_t ws_size,
                              hipStream_t stream) {
  const float* x    = (const float*)d_in[0];
  const float* Wih1 = (const float*)d_in[1];
  const float* Whh1 = (const float*)d_in[2];
  const float* b1   = (const float*)d_in[3];
  const float* Wih2 = (const float*)d_in[4];
  const float* Whh2 = (const float*)d_in[5];
  const float* b2   = (const float*)d_in[6];
  const float* Wih3 = (const float*)d_in[7];
  const float* Whh3 = (const float*)d_in[8];
  const float* b3   = (const float*)d_in[9];
  const float* Wih4 = (const float*)d_in[10];
  const float* Whh4 = (const float*)d_in[11];
  const float* b4   = (const float*)d_in[12];
  const float* Wout = (const float*)d_in[13];
  const float* bout = (const float*)d_in[14];
  float* out = (float*)d_out;

  const int B = in_sizes[0] / (TT * FF);   // 8192
  dim3 grid(B / 16), block(512);
  lstm_ae_mfma5<<<grid, block, 0, stream>>>(
      x, Wih1, Whh1, b1, Wih2, Whh2, b2, Wih3, Whh3, b3,
      Wih4, Whh4, b4, Wout, bout, out);
}